// Round 13
// baseline (3325.363 us; speedup 1.0000x reference)
//
#include <hip/hip_runtime.h>

typedef unsigned short u16;
typedef unsigned int   u32;

typedef __attribute__((ext_vector_type(8)))  short bf16x8;
typedef __attribute__((ext_vector_type(4)))  float f32x4;
typedef __attribute__((ext_vector_type(8)))  u32   u32x8;
typedef __attribute__((ext_vector_type(16))) float f32x16;

#define B_  32
#define S_  1024
#define NH_ 512
#define G4_ 2048   // 4*NH
#define SC_NWG 32  // scan workgroups on the winning XCD (2 waves each)
#define CAND  256  // election candidates (1 per CU via LDS pad)

__device__ __forceinline__ float bf2f(u16 h) {
    return __uint_as_float(((u32)h) << 16);
}
__device__ __forceinline__ u16 f2bf(float f) {
    u32 u = __float_as_uint(f);
    return (u16)((u + 0x7fffu + ((u >> 16) & 1u)) >> 16);
}
__device__ __forceinline__ float fsig(float x) {
    return 1.0f / (1.0f + __expf(-x));
}
__device__ __forceinline__ float ftanh(float x) {
    return 1.0f - 2.0f / (__expf(2.0f * x) + 1.0f);
}

// ---------------- fp32 -> bf16 elementwise convert (vectorized x4) ----------
__global__ void cvt_bf16_kernel(const float* __restrict__ in, u16* __restrict__ out, int n4) {
    int i = blockIdx.x * blockDim.x + threadIdx.x;
    if (i >= n4) return;
    f32x4 v = ((const f32x4*)in)[i];
    unsigned long long pk =
        (unsigned long long)f2bf(v[0]) |
        ((unsigned long long)f2bf(v[1]) << 16) |
        ((unsigned long long)f2bf(v[2]) << 32) |
        ((unsigned long long)f2bf(v[3]) << 48);
    ((unsigned long long*)out)[i] = pk;
}

// ---------------- fp32 [R][C] -> bf16 [C][R] transpose-convert --------------
__global__ void transpose_cvt_kernel(const float* __restrict__ in, u16* __restrict__ out,
                                     int R, int C) {
    __shared__ float tile[32][33];
    int bx = blockIdx.x, by = blockIdx.y;
    int tx = threadIdx.x & 31, ty = threadIdx.x >> 5;
    #pragma unroll
    for (int i = 0; i < 4; i++) {
        int r = by * 32 + ty + i * 8;
        tile[ty + i * 8][tx] = in[(size_t)r * C + bx * 32 + tx];
    }
    __syncthreads();
    #pragma unroll
    for (int i = 0; i < 4; i++) {
        int c = bx * 32 + ty + i * 8;
        out[(size_t)c * R + by * 32 + tx] = f2bf(tile[tx][ty + i * 8]);
    }
}

// ---------------- generic bf16 MFMA GEMM: C = A @ BT^T + bias ---------------
// A [M][K] bf16 row-major, BT [N][K] bf16, bias [N] f32.
// out_mode: 0 -> f32 row-major; 1 -> bf16 in SCAN ORDER [t][wg64][lane][r]
__global__ __launch_bounds__(256) void gemm_bf16_kernel(
    const u16* __restrict__ A, const u16* __restrict__ BT,
    const float* __restrict__ bias, void* __restrict__ Cp,
    int M, int N, int K, int out_mode)
{
    __shared__ u16 Al[128][40];
    __shared__ u16 Bl[128][40];
    int nbm = M >> 7;
    int bm = blockIdx.x % nbm, bn = blockIdx.x / nbm;
    int tid = threadIdx.x, lane = tid & 63, wave = tid >> 6;
    int wr = wave >> 1, wc = wave & 1;
    f32x4 acc[4][4];
    #pragma unroll
    for (int i = 0; i < 4; i++)
        #pragma unroll
        for (int j = 0; j < 4; j++)
            acc[i][j] = (f32x4){0.f, 0.f, 0.f, 0.f};
    int fr  = lane & 15;
    int kof = (lane >> 4) << 3;

    for (int k0 = 0; k0 < K; k0 += 32) {
        __syncthreads();
        #pragma unroll
        for (int i = 0; i < 2; i++) {
            int chunk = i * 256 + tid;
            int r = chunk >> 2, c = (chunk & 3) << 3;
            *(bf16x8*)&Al[r][c] = *(const bf16x8*)&A[(size_t)(bm * 128 + r) * K + k0 + c];
            *(bf16x8*)&Bl[r][c] = *(const bf16x8*)&BT[(size_t)(bn * 128 + r) * K + k0 + c];
        }
        __syncthreads();
        bf16x8 af[4], bfr[4];
        #pragma unroll
        for (int mi = 0; mi < 4; mi++)
            af[mi] = *(const bf16x8*)&Al[wr * 64 + mi * 16 + fr][kof];
        #pragma unroll
        for (int ni = 0; ni < 4; ni++)
            bfr[ni] = *(const bf16x8*)&Bl[wc * 64 + ni * 16 + fr][kof];
        #pragma unroll
        for (int mi = 0; mi < 4; mi++)
            #pragma unroll
            for (int ni = 0; ni < 4; ni++)
                acc[mi][ni] = __builtin_amdgcn_mfma_f32_16x16x32_bf16(af[mi], bfr[ni], acc[mi][ni], 0, 0, 0);
    }
    int rq = lane >> 4;
    #pragma unroll
    for (int mi = 0; mi < 4; mi++) {
        #pragma unroll
        for (int ni = 0; ni < 4; ni++) {
            int n = bn * 128 + wc * 64 + ni * 16 + fr;
            float bv = bias ? bias[n] : 0.f;
            #pragma unroll
            for (int r = 0; r < 4; r++) {
                int m = bm * 128 + wr * 64 + mi * 16 + rq * 4 + r;
                float v = acc[mi][ni][r] + bv;
                if (out_mode == 1) {
                    // scan-order store: [t][wg64][lane2][r2]  (validated round 4)
                    int t = m & 1023, b = m >> 10;
                    int g_loc = n >> 9, wg64i = (n >> 3) & 63, u_loc = n & 7;
                    int lane2 = (((b >> 2) & 1) << 5) | (u_loc << 2) | g_loc;
                    int r2 = (b & 3) | ((b >> 3) << 2);
                    ((u16*)Cp)[(((size_t)t * 64 + wg64i) * 64 + lane2) * 16 + r2] = f2bf(v);
                } else {
                    ((float*)Cp)[(size_t)m * N + n] = v;
                }
            }
        }
    }
}

// ---------------- LSTM scan: 32 same-XCD WGs x 2 waves ----------------------
// Protocol identical to rounds 10-12 (validated: FETCH 66MB, scalar poll):
// election -> intra-XCD L2 messaging; scalar-cache poll (s_dcache_inv +
// s_load_dwordx8 x4, contention-free); one buffer_inv + plain bulk reads;
// plain h stores -> vmcnt(0) -> barrier -> per-WG flag.
// CHANGE (continuing r12's confirmed curve): 32 WGs x 2 waves -- same 64
// wave-slots over 4x the CUs of r11. Per-CU MFMA serialization 64 MFMA x
// ~8cy = 512 cy/step. 40KB LDS pad (live via volatile read) -> 1 WG/CU;
// 256 candidates on 256 CUs = exactly 32 per XCD, winner uses all 32.
__global__ __launch_bounds__(128, 1) void lstm_scan_kernel(
    const u16* __restrict__ xw,    // [S][64][64][16] bf16 scan-order
    const u16* __restrict__ UT,    // [4H][NH] bf16
    u16* __restrict__ hseq,        // [B][S][NH] bf16
    u16* __restrict__ hbuf,        // [2][32][512] bf16
    u32* __restrict__ flags,       // [32] per-WG progress
    u32* __restrict__ elect,       // [8] per-XCD registration counters
    int* __restrict__ winner)      // winning XCD id, init -1
{
    __shared__ int s_role;
    __shared__ u16 h_lds[32][520];      // [batch][k], +8 u16 pad (0-conflict, r2)
    __shared__ float gl[2][32][32];     // per-wave gate exchange
    __shared__ u32 lds_pad[10240];      // 40KB occupancy pad -> 1 WG/CU

    const int tid = threadIdx.x;

    // keep the pad allocated: volatile LDS read cannot be DCE'd (r12-proven)
    lds_pad[tid] = (u32)tid;
    {
        volatile u32* vp = lds_pad;
        u32 dummy = vp[tid];
        asm volatile("" :: "v"(dummy));
    }

    if (tid == 0) {
        u32 xcc;
        asm volatile("s_getreg_b32 %0, hwreg(HW_REG_XCC_ID)" : "=s"(xcc));
        xcc &= 7u;
        u32 r = __hip_atomic_fetch_add(&elect[xcc], 1u,
                    __ATOMIC_ACQ_REL, __HIP_MEMORY_SCOPE_AGENT);
        int role = -1;
        if (r < (u32)SC_NWG) {
            if (r == (u32)SC_NWG - 1) {   // our XCD just reached 32: try claim
                int expv = -1;
                __hip_atomic_compare_exchange_strong(winner, &expv, (int)xcc,
                    __ATOMIC_ACQ_REL, __ATOMIC_ACQUIRE, __HIP_MEMORY_SCOPE_AGENT);
            }
            int w = -1;
            for (int spins = 0; spins < 200000; spins++) {   // bounded
                w = __hip_atomic_load(winner, __ATOMIC_ACQUIRE,
                                      __HIP_MEMORY_SCOPE_AGENT);
                if (w >= 0) break;
                __builtin_amdgcn_s_sleep(8);
            }
            role = (w == (int)xcc) ? (int)r : -1;
        }
        s_role = role;
    }
    __syncthreads();
    const int role = s_role;
    if (role < 0) return;

    const int wave = tid >> 6, lane = tid & 63;
    const int wg64 = role * 2 + wave;
    const int col  = lane & 31, half = lane >> 5;
    const int u_loc = col >> 2, g_loc = col & 3;
    const int ucol  = g_loc * 512 + wg64 * 8 + u_loc;

    // U B-fragments (asm loads, r11)
    bf16x8 ufrag[32];
    {
        const u16* ub = &UT[(size_t)ucol * 512 + half * 8];
        #define LDU4(i0)                                                      \
            asm volatile(                                                     \
                "global_load_dwordx4 %0, %4, off\n\t"                         \
                "global_load_dwordx4 %1, %4, off offset:32\n\t"               \
                "global_load_dwordx4 %2, %4, off offset:64\n\t"               \
                "global_load_dwordx4 %3, %4, off offset:96"                   \
                : "=&v"(ufrag[i0]), "=&v"(ufrag[i0 + 1]),                     \
                  "=&v"(ufrag[i0 + 2]), "=&v"(ufrag[i0 + 3])                  \
                : "v"(ub + (i0) * 16))
        LDU4(0); LDU4(4); LDU4(8); LDU4(12);
        LDU4(16); LDU4(20); LDU4(24); LDU4(28);
        #undef LDU4
        asm volatile("s_waitcnt vmcnt(0)" ::: "memory");
    }

    float cst[4] = {0.f, 0.f, 0.f, 0.f};

    // h(0) = 0 in LDS (t=0 skips the poll)
    {
        bf16x8 z = (bf16x8){0, 0, 0, 0, 0, 0, 0, 0};
        bf16x8* hf = (bf16x8*)&h_lds[0][0];
        for (int i = tid; i < 2080; i += 128) hf[i] = z;
    }

    const int sb_b  = tid >> 4;   // base row 0..7 (handles rows sb_b + 8k)
    const int sb_ic = tid & 15;   // 16B chunk, 256B-strided (0-conflict, r2)

    for (int t = 0; t < 1024; t++) {
        // xw for this step: 32B contiguous per lane, issued early
        const u16* xp = xw + ((size_t)((size_t)t * 64 + wg64) * 64 + lane) * 16;
        bf16x8 xv0 = *(const bf16x8*)xp;
        bf16x8 xv1 = *(const bf16x8*)(xp + 8);

        if (t > 0) {
            const u32 tg = (u32)t;
            // ---- scalar-cache poll: 4 SMEM ops/wave/round, contention-free ----
            {
                u32x8 f0, f1, f2, f3;
                int rounds = 0;
                while (1) {
                    asm volatile("s_dcache_inv\n\t"
                                 "s_load_dwordx8 %0, %4, 0x0\n\t"
                                 "s_load_dwordx8 %1, %4, 0x20\n\t"
                                 "s_load_dwordx8 %2, %4, 0x40\n\t"
                                 "s_load_dwordx8 %3, %4, 0x60\n\t"
                                 "s_waitcnt lgkmcnt(0)"
                                 : "=s"(f0), "=s"(f1), "=s"(f2), "=s"(f3)
                                 : "s"(flags) : "memory");
                    bool ok = true;
                    #pragma unroll
                    for (int q = 0; q < 8; q++) {
                        ok = ok && f0[q] >= tg && f1[q] >= tg &&
                                   f2[q] >= tg && f3[q] >= tg;
                    }
                    if (ok || ++rounds > (1 << 13)) break;
                }
            }
            // one L1 invalidate, then plain bulk reads served by shared L2
            asm volatile("buffer_inv" ::: "memory");
            const char* sb0 = (const char*)(hbuf + ((size_t)(t & 1) << 14))
                              + sb_b * 1024 + sb_ic * 16;
            f32x4 r0, r1, r2, r3, r4, r5, r6, r7;
            // rows sb_b, sb_b+8
            asm volatile(
                "global_load_dwordx4 %0, %8, off\n\t"
                "global_load_dwordx4 %1, %8, off offset:256\n\t"
                "global_load_dwordx4 %2, %8, off offset:512\n\t"
                "global_load_dwordx4 %3, %8, off offset:768\n\t"
                "global_load_dwordx4 %4, %9, off\n\t"
                "global_load_dwordx4 %5, %9, off offset:256\n\t"
                "global_load_dwordx4 %6, %9, off offset:512\n\t"
                "global_load_dwordx4 %7, %9, off offset:768\n\t"
                "s_waitcnt vmcnt(0)"
                : "=&v"(r0), "=&v"(r1), "=&v"(r2), "=&v"(r3),
                  "=&v"(r4), "=&v"(r5), "=&v"(r6), "=&v"(r7)
                : "v"(sb0), "v"(sb0 + 8192) : "memory");
            {
                u16* d0 = &h_lds[sb_b][sb_ic * 8];
                u16* d1 = &h_lds[sb_b + 8][sb_ic * 8];
                *(f32x4*)(d0) = r0; *(f32x4*)(d0 + 128) = r1;
                *(f32x4*)(d0 + 256) = r2; *(f32x4*)(d0 + 384) = r3;
                *(f32x4*)(d1) = r4; *(f32x4*)(d1 + 128) = r5;
                *(f32x4*)(d1 + 256) = r6; *(f32x4*)(d1 + 384) = r7;
            }
            // rows sb_b+16, sb_b+24
            asm volatile(
                "global_load_dwordx4 %0, %8, off\n\t"
                "global_load_dwordx4 %1, %8, off offset:256\n\t"
                "global_load_dwordx4 %2, %8, off offset:512\n\t"
                "global_load_dwordx4 %3, %8, off offset:768\n\t"
                "global_load_dwordx4 %4, %9, off\n\t"
                "global_load_dwordx4 %5, %9, off offset:256\n\t"
                "global_load_dwordx4 %6, %9, off offset:512\n\t"
                "global_load_dwordx4 %7, %9, off offset:768\n\t"
                "s_waitcnt vmcnt(0)"
                : "=&v"(r0), "=&v"(r1), "=&v"(r2), "=&v"(r3),
                  "=&v"(r4), "=&v"(r5), "=&v"(r6), "=&v"(r7)
                : "v"(sb0 + 16384), "v"(sb0 + 24576) : "memory");
            __builtin_amdgcn_sched_barrier(0);
            {
                u16* d2 = &h_lds[sb_b + 16][sb_ic * 8];
                u16* d3 = &h_lds[sb_b + 24][sb_ic * 8];
                *(f32x4*)(d2) = r0; *(f32x4*)(d2 + 128) = r1;
                *(f32x4*)(d2 + 256) = r2; *(f32x4*)(d2 + 384) = r3;
                *(f32x4*)(d3) = r4; *(f32x4*)(d3 + 128) = r5;
                *(f32x4*)(d3 + 256) = r6; *(f32x4*)(d3 + 384) = r7;
            }
        }
        __syncthreads();

        // gates = h @ Uslice: 2 accumulators halve the dependent-MFMA chain
        f32x16 a0 = {0,0,0,0, 0,0,0,0, 0,0,0,0, 0,0,0,0};
        f32x16 a1 = {0,0,0,0, 0,0,0,0, 0,0,0,0, 0,0,0,0};
        #pragma unroll
        for (int kk = 0; kk < 16; kk++) {
            bf16x8 af0 = *(const bf16x8*)&h_lds[col][kk * 16 + half * 8];
            a0 = __builtin_amdgcn_mfma_f32_32x32x16_bf16(af0, ufrag[kk], a0, 0, 0, 0);
            bf16x8 af1 = *(const bf16x8*)&h_lds[col][(kk + 16) * 16 + half * 8];
            a1 = __builtin_amdgcn_mfma_f32_32x32x16_bf16(af1, ufrag[kk + 16], a1, 0, 0, 0);
        }

        // gate exchange (wave-local LDS; in-wave lgkmcnt ordering, no barrier)
        #pragma unroll
        for (int r = 0; r < 16; r++) {
            int b = (r & 3) + ((r >> 2) << 3) + (half << 2);
            float xwv = bf2f(r < 8 ? (u16)xv0[r] : (u16)xv1[r - 8]);
            gl[wave][b][col] = a0[r] + a1[r] + xwv;
        }

        // cell update: compute 4 results, then burst plain h stores
        u16 hv[4];
        int bi[4];
        #pragma unroll
        for (int i = 0; i < 4; i++) {
            int p = (i << 6) + lane, b = p >> 3, u = p & 7;
            f32x4 g4 = *(const f32x4*)&gl[wave][b][u << 2];   // i,f,g,o
            float si = fsig(g4[0]), sf = fsig(g4[1]);
            float sg = ftanh(g4[2]), so = fsig(g4[3]);
            float c = sf * cst[i] + si * sg;
            cst[i] = c;
            hv[i] = f2bf(so * ftanh(c));
            bi[i] = b;
        }
        u16* hb_out = hbuf + ((size_t)(((size_t)t + 1) & 1) << 14);
        const int j = (wg64 << 3);
        #pragma unroll
        for (int i = 0; i < 4; i++) {
            int p = (i << 6) + lane, u = p & 7;
            u32 hw = hv[i];
            u16* hp = hb_out + bi[i] * 512 + j + u;
            asm volatile("global_store_short %0, %1, off"
                         :: "v"(hp), "v"(hw) : "memory");
        }
        // drain to shared L2, WG barrier, publish per-WG flag
        asm volatile("s_waitcnt vmcnt(0)" ::: "memory");
        __syncthreads();
        if (tid == 0) {
            u32 fv = (u32)(t + 1);
            u32* fq = flags + role;
            asm volatile("global_store_dword %0, %1, off"
                         :: "v"(fq), "v"(fv) : "memory");
        }
        // hseq: plain cached stores, off the critical path
        #pragma unroll
        for (int i = 0; i < 4; i++) {
            int p = (i << 6) + lane, u = p & 7;
            hseq[((size_t)bi[i] * S_ + t) * NH_ + j + u] = hv[i];
        }
    }
}

extern "C" void kernel_launch(void* const* d_in, const int* in_sizes, int n_in,
                              void* d_out, int out_size, void* d_ws, size_t ws_size,
                              hipStream_t stream) {
    const float* x        = (const float*)d_in[0];
    const float* W        = (const float*)d_in[1];
    const float* U        = (const float*)d_in[2];
    const float* hid_bias = (const float*)d_in[3];
    const float* V        = (const float*)d_in[4];
    const float* out_bias = (const float*)d_in[5];

    char* ws = (char*)d_ws;
    size_t off = 0;
    auto carve = [&](size_t bytes) -> void* {
        void* p = ws + off;
        off += (bytes + 255) & ~(size_t)255;
        return p;
    };
    u16* xw     = (u16*)carve((size_t)B_ * S_ * G4_ * 2);   // 128 MB, scan-order
    u16* xbf    = (u16*)carve((size_t)B_ * S_ * NH_ * 2);   //  32 MB
    u16* hseq   = (u16*)carve((size_t)B_ * S_ * NH_ * 2);   //  32 MB
    u16* WT     = (u16*)carve((size_t)G4_ * NH_ * 2);       //   2 MB
    u16* UT     = (u16*)carve((size_t)G4_ * NH_ * 2);       //   2 MB
    u16* VT     = (u16*)carve((size_t)NH_ * NH_ * 2);       // 512 KB
    u16* hbuf   = (u16*)carve((size_t)2 * B_ * NH_ * 2);    //  64 KB
    u32* flags  = (u32*)carve(256);
    u32* elect  = (u32*)carve(256);
    int* winner = (int*)carve(256);

    hipMemsetAsync(flags, 0, 256, stream);
    hipMemsetAsync(elect, 0, 256, stream);
    hipMemsetAsync(winner, 0xFF, 256, stream);   // winner = -1

    int n4 = B_ * S_ * NH_ / 4;
    cvt_bf16_kernel<<<(n4 + 255) / 256, 256, 0, stream>>>(x, xbf, n4);
    transpose_cvt_kernel<<<dim3(G4_ / 32, NH_ / 32), 256, 0, stream>>>(W, WT, NH_, G4_);
    transpose_cvt_kernel<<<dim3(G4_ / 32, NH_ / 32), 256, 0, stream>>>(U, UT, NH_, G4_);
    transpose_cvt_kernel<<<dim3(NH_ / 32, NH_ / 32), 256, 0, stream>>>(V, VT, NH_, NH_);

    // xW + hid_bias -> bf16, stored in scan order
    gemm_bf16_kernel<<<4096, 256, 0, stream>>>(xbf, WT, hid_bias, xw,
                                               B_ * S_, G4_, NH_, 1);
    // sequential LSTM scan (same-XCD election inside)
    lstm_scan_kernel<<<CAND, 128, 0, stream>>>(xw, UT, hseq, hbuf,
                                               flags, elect, winner);
    // out = hseq @ V + out_bias -> f32
    gemm_bf16_kernel<<<1024, 256, 0, stream>>>(hseq, VT, out_bias, d_out,
                                               B_ * S_, NH_, NH_, 0);
}

// Round 14
// 3313.977 us; speedup vs baseline: 1.0034x; 1.0034x over previous
//
#include <hip/hip_runtime.h>

typedef unsigned short u16;
typedef unsigned int   u32;

typedef __attribute__((ext_vector_type(8)))  short bf16x8;
typedef __attribute__((ext_vector_type(4)))  float f32x4;
typedef __attribute__((ext_vector_type(16))) float f32x16;

#define B_  32
#define S_  1024
#define NH_ 512
#define G4_ 2048   // 4*NH
#define SC_NWG 16  // scan workgroups on the winning XCD (4 waves each) -- r12 optimum
#define CAND  256  // election candidates

__device__ __forceinline__ float bf2f(u16 h) {
    return __uint_as_float(((u32)h) << 16);
}
__device__ __forceinline__ u16 f2bf(float f) {
    u32 u = __float_as_uint(f);
    return (u16)((u + 0x7fffu + ((u >> 16) & 1u)) >> 16);
}
__device__ __forceinline__ float fsig(float x) {
    return 1.0f / (1.0f + __expf(-x));
}
__device__ __forceinline__ float ftanh(float x) {
    return 1.0f - 2.0f / (__expf(2.0f * x) + 1.0f);
}

// ---------------- fp32 -> bf16 elementwise convert (vectorized x4) ----------
__global__ void cvt_bf16_kernel(const float* __restrict__ in, u16* __restrict__ out, int n4) {
    int i = blockIdx.x * blockDim.x + threadIdx.x;
    if (i >= n4) return;
    f32x4 v = ((const f32x4*)in)[i];
    unsigned long long pk =
        (unsigned long long)f2bf(v[0]) |
        ((unsigned long long)f2bf(v[1]) << 16) |
        ((unsigned long long)f2bf(v[2]) << 32) |
        ((unsigned long long)f2bf(v[3]) << 48);
    ((unsigned long long*)out)[i] = pk;
}

// ---------------- fp32 [R][C] -> bf16 [C][R] transpose-convert --------------
__global__ void transpose_cvt_kernel(const float* __restrict__ in, u16* __restrict__ out,
                                     int R, int C) {
    __shared__ float tile[32][33];
    int bx = blockIdx.x, by = blockIdx.y;
    int tx = threadIdx.x & 31, ty = threadIdx.x >> 5;
    #pragma unroll
    for (int i = 0; i < 4; i++) {
        int r = by * 32 + ty + i * 8;
        tile[ty + i * 8][tx] = in[(size_t)r * C + bx * 32 + tx];
    }
    __syncthreads();
    #pragma unroll
    for (int i = 0; i < 4; i++) {
        int c = bx * 32 + ty + i * 8;
        out[(size_t)c * R + by * 32 + tx] = f2bf(tile[tx][ty + i * 8]);
    }
}

// ---------------- generic bf16 MFMA GEMM: C = A @ BT^T + bias ---------------
// A [M][K] bf16 row-major, BT [N][K] bf16, bias [N] f32.
// out_mode: 0 -> f32 row-major; 1 -> bf16 in SCAN ORDER [t][wg64][lane][r]
__global__ __launch_bounds__(256) void gemm_bf16_kernel(
    const u16* __restrict__ A, const u16* __restrict__ BT,
    const float* __restrict__ bias, void* __restrict__ Cp,
    int M, int N, int K, int out_mode)
{
    __shared__ u16 Al[128][40];
    __shared__ u16 Bl[128][40];
    int nbm = M >> 7;
    int bm = blockIdx.x % nbm, bn = blockIdx.x / nbm;
    int tid = threadIdx.x, lane = tid & 63, wave = tid >> 6;
    int wr = wave >> 1, wc = wave & 1;
    f32x4 acc[4][4];
    #pragma unroll
    for (int i = 0; i < 4; i++)
        #pragma unroll
        for (int j = 0; j < 4; j++)
            acc[i][j] = (f32x4){0.f, 0.f, 0.f, 0.f};
    int fr  = lane & 15;
    int kof = (lane >> 4) << 3;

    for (int k0 = 0; k0 < K; k0 += 32) {
        __syncthreads();
        #pragma unroll
        for (int i = 0; i < 2; i++) {
            int chunk = i * 256 + tid;
            int r = chunk >> 2, c = (chunk & 3) << 3;
            *(bf16x8*)&Al[r][c] = *(const bf16x8*)&A[(size_t)(bm * 128 + r) * K + k0 + c];
            *(bf16x8*)&Bl[r][c] = *(const bf16x8*)&BT[(size_t)(bn * 128 + r) * K + k0 + c];
        }
        __syncthreads();
        bf16x8 af[4], bfr[4];
        #pragma unroll
        for (int mi = 0; mi < 4; mi++)
            af[mi] = *(const bf16x8*)&Al[wr * 64 + mi * 16 + fr][kof];
        #pragma unroll
        for (int ni = 0; ni < 4; ni++)
            bfr[ni] = *(const bf16x8*)&Bl[wc * 64 + ni * 16 + fr][kof];
        #pragma unroll
        for (int mi = 0; mi < 4; mi++)
            #pragma unroll
            for (int ni = 0; ni < 4; ni++)
                acc[mi][ni] = __builtin_amdgcn_mfma_f32_16x16x32_bf16(af[mi], bfr[ni], acc[mi][ni], 0, 0, 0);
    }
    int rq = lane >> 4;
    #pragma unroll
    for (int mi = 0; mi < 4; mi++) {
        #pragma unroll
        for (int ni = 0; ni < 4; ni++) {
            int n = bn * 128 + wc * 64 + ni * 16 + fr;
            float bv = bias ? bias[n] : 0.f;
            #pragma unroll
            for (int r = 0; r < 4; r++) {
                int m = bm * 128 + wr * 64 + mi * 16 + rq * 4 + r;
                float v = acc[mi][ni][r] + bv;
                if (out_mode == 1) {
                    // scan-order store: [t][wg64][lane2][r2]  (validated round 4)
                    int t = m & 1023, b = m >> 10;
                    int g_loc = n >> 9, wg64i = (n >> 3) & 63, u_loc = n & 7;
                    int lane2 = (((b >> 2) & 1) << 5) | (u_loc << 2) | g_loc;
                    int r2 = (b & 3) | ((b >> 3) << 2);
                    ((u16*)Cp)[(((size_t)t * 64 + wg64i) * 64 + lane2) * 16 + r2] = f2bf(v);
                } else {
                    ((float*)Cp)[(size_t)m * N + n] = v;
                }
            }
        }
    }
}

// ---------------- LSTM scan: 16 same-XCD WGs x 4 waves (r12 optimum) --------
// Protocol = rounds 10-12 (validated). Three latency shavings this round:
//  (a) xw prefetch for t+1 issued at loop TAIL (after flag publish) into
//      loop-carried registers -- r12 issued at loop top, so the stage
//      vmcnt(0) ~600cy later ate up to ~700cy of xw HBM latency per step.
//  (b) flags strided 64B apart (one L2 line per WG) -- r12's 16 stores to
//      ONE line serialized at the L2 bank, delaying the last flag ~300-500cy.
//  (c) buffer_inv hoisted BEFORE the poll (no hbuf vector reads occur
//      between inv and the bulk loads, so freshness is preserved).
__global__ __launch_bounds__(256, 1) void lstm_scan_kernel(
    const u16* __restrict__ xw,    // [S][64][64][16] bf16 scan-order
    const u16* __restrict__ UT,    // [4H][NH] bf16
    u16* __restrict__ hseq,        // [B][S][NH] bf16
    u16* __restrict__ hbuf,        // [2][32][512] bf16
    u32* __restrict__ flags,       // [16 x 16] progress, 64B stride
    u32* __restrict__ elect,       // [8] per-XCD registration counters
    int* __restrict__ winner)      // winning XCD id, init -1
{
    __shared__ int s_role;
    __shared__ u16 h_lds[32][520];      // [batch][k], +8 u16 pad (0-conflict, r2)
    __shared__ float gl[4][32][32];     // per-wave gate exchange
    __shared__ u32 lds_pad[10240];      // 40KB occupancy pad -> 1 WG/CU

    const int tid = threadIdx.x;

    // keep the pad allocated: volatile LDS read cannot be DCE'd (r12-proven)
    lds_pad[tid] = (u32)tid;
    {
        volatile u32* vp = lds_pad;
        u32 dummy = vp[tid];
        asm volatile("" :: "v"(dummy));
    }

    if (tid == 0) {
        u32 xcc;
        asm volatile("s_getreg_b32 %0, hwreg(HW_REG_XCC_ID)" : "=s"(xcc));
        xcc &= 7u;
        u32 r = __hip_atomic_fetch_add(&elect[xcc], 1u,
                    __ATOMIC_ACQ_REL, __HIP_MEMORY_SCOPE_AGENT);
        int role = -1;
        if (r < (u32)SC_NWG) {
            if (r == (u32)SC_NWG - 1) {   // our XCD just reached 16: try claim
                int expv = -1;
                __hip_atomic_compare_exchange_strong(winner, &expv, (int)xcc,
                    __ATOMIC_ACQ_REL, __ATOMIC_ACQUIRE, __HIP_MEMORY_SCOPE_AGENT);
            }
            int w = -1;
            for (int spins = 0; spins < 200000; spins++) {   // bounded
                w = __hip_atomic_load(winner, __ATOMIC_ACQUIRE,
                                      __HIP_MEMORY_SCOPE_AGENT);
                if (w >= 0) break;
                __builtin_amdgcn_s_sleep(8);
            }
            role = (w == (int)xcc) ? (int)r : -1;
        }
        s_role = role;
    }
    __syncthreads();
    const int role = s_role;
    if (role < 0) return;

    const int wave = tid >> 6, lane = tid & 63;
    const int wg64 = role * 4 + wave;
    const int col  = lane & 31, half = lane >> 5;
    const int u_loc = col >> 2, g_loc = col & 3;
    const int ucol  = g_loc * 512 + wg64 * 8 + u_loc;

    // U B-fragments (asm loads, r11)
    bf16x8 ufrag[32];
    {
        const u16* ub = &UT[(size_t)ucol * 512 + half * 8];
        #define LDU4(i0)                                                      \
            asm volatile(                                                     \
                "global_load_dwordx4 %0, %4, off\n\t"                         \
                "global_load_dwordx4 %1, %4, off offset:32\n\t"               \
                "global_load_dwordx4 %2, %4, off offset:64\n\t"               \
                "global_load_dwordx4 %3, %4, off offset:96"                   \
                : "=&v"(ufrag[i0]), "=&v"(ufrag[i0 + 1]),                     \
                  "=&v"(ufrag[i0 + 2]), "=&v"(ufrag[i0 + 3])                  \
                : "v"(ub + (i0) * 16))
        LDU4(0); LDU4(4); LDU4(8); LDU4(12);
        LDU4(16); LDU4(20); LDU4(24); LDU4(28);
        #undef LDU4
        asm volatile("s_waitcnt vmcnt(0)" ::: "memory");
    }

    float cst[4] = {0.f, 0.f, 0.f, 0.f};

    // h(0) = 0 in LDS (t=0 skips the poll)
    {
        bf16x8 z = (bf16x8){0, 0, 0, 0, 0, 0, 0, 0};
        bf16x8* hf = (bf16x8*)&h_lds[0][0];
        for (int i = tid; i < 2080; i += 256) hf[i] = z;
    }

    const int sb_b  = tid >> 4;   // base row 0..15 (handles sb_b, sb_b+16)
    const int sb_ic = tid & 15;   // 16B chunk, 256B-strided (0-conflict, r2)

    // prologue: xw(0) prefetch into loop-carried registers
    bf16x8 xv0, xv1;
    {
        const u16* xp0 = xw + ((size_t)wg64 * 64 + lane) * 16;
        asm volatile("global_load_dwordx4 %0, %2, off\n\t"
                     "global_load_dwordx4 %1, %2, off offset:16\n\t"
                     "s_waitcnt vmcnt(0)"
                     : "=&v"(xv0), "=&v"(xv1) : "v"(xp0) : "memory");
    }

    for (int t = 0; t < 1024; t++) {
        if (t > 0) {
            const u32 tg = (u32)t;
            // (c) L1 invalidate BEFORE the poll -- off the serial path
            asm volatile("buffer_inv" ::: "memory");
            // scalar-cache poll: 16 flags on 16 distinct L2 lines (b)
            {
                u32 f0, f1, f2, f3, f4, f5, f6, f7;
                u32 f8, f9, fa, fb, fc, fd, fe, ff;
                int rounds = 0;
                while (1) {
                    asm volatile(
                        "s_dcache_inv\n\t"
                        "s_load_dword %0, %16, 0x0\n\t"
                        "s_load_dword %1, %16, 0x40\n\t"
                        "s_load_dword %2, %16, 0x80\n\t"
                        "s_load_dword %3, %16, 0xC0\n\t"
                        "s_load_dword %4, %16, 0x100\n\t"
                        "s_load_dword %5, %16, 0x140\n\t"
                        "s_load_dword %6, %16, 0x180\n\t"
                        "s_load_dword %7, %16, 0x1C0\n\t"
                        "s_load_dword %8, %16, 0x200\n\t"
                        "s_load_dword %9, %16, 0x240\n\t"
                        "s_load_dword %10, %16, 0x280\n\t"
                        "s_load_dword %11, %16, 0x2C0\n\t"
                        "s_load_dword %12, %16, 0x300\n\t"
                        "s_load_dword %13, %16, 0x340\n\t"
                        "s_load_dword %14, %16, 0x380\n\t"
                        "s_load_dword %15, %16, 0x3C0\n\t"
                        "s_waitcnt lgkmcnt(0)"
                        : "=s"(f0), "=s"(f1), "=s"(f2), "=s"(f3),
                          "=s"(f4), "=s"(f5), "=s"(f6), "=s"(f7),
                          "=s"(f8), "=s"(f9), "=s"(fa), "=s"(fb),
                          "=s"(fc), "=s"(fd), "=s"(fe), "=s"(ff)
                        : "s"(flags) : "memory");
                    bool ok = f0 >= tg && f1 >= tg && f2 >= tg && f3 >= tg &&
                              f4 >= tg && f5 >= tg && f6 >= tg && f7 >= tg &&
                              f8 >= tg && f9 >= tg && fa >= tg && fb >= tg &&
                              fc >= tg && fd >= tg && fe >= tg && ff >= tg;
                    if (ok || ++rounds > (1 << 13)) break;
                }
            }
            // bulk h reads from shared L2 (L1 already invalidated above)
            const char* sb0 = (const char*)(hbuf + ((size_t)(t & 1) << 14))
                              + sb_b * 1024 + sb_ic * 16;
            f32x4 r0, r1, r2, r3, r4, r5, r6, r7;
            asm volatile(
                "global_load_dwordx4 %0, %8, off\n\t"
                "global_load_dwordx4 %1, %8, off offset:256\n\t"
                "global_load_dwordx4 %2, %8, off offset:512\n\t"
                "global_load_dwordx4 %3, %8, off offset:768\n\t"
                "global_load_dwordx4 %4, %9, off\n\t"
                "global_load_dwordx4 %5, %9, off offset:256\n\t"
                "global_load_dwordx4 %6, %9, off offset:512\n\t"
                "global_load_dwordx4 %7, %9, off offset:768\n\t"
                "s_waitcnt vmcnt(0)"
                : "=&v"(r0), "=&v"(r1), "=&v"(r2), "=&v"(r3),
                  "=&v"(r4), "=&v"(r5), "=&v"(r6), "=&v"(r7)
                : "v"(sb0), "v"(sb0 + 16384) : "memory");
            __builtin_amdgcn_sched_barrier(0);
            u16* d0 = &h_lds[sb_b][sb_ic * 8];
            u16* d1 = &h_lds[sb_b + 16][sb_ic * 8];
            *(f32x4*)(d0)       = r0;
            *(f32x4*)(d0 + 128) = r1;
            *(f32x4*)(d0 + 256) = r2;
            *(f32x4*)(d0 + 384) = r3;
            *(f32x4*)(d1)       = r4;
            *(f32x4*)(d1 + 128) = r5;
            *(f32x4*)(d1 + 256) = r6;
            *(f32x4*)(d1 + 384) = r7;
        }
        __syncthreads();

        // gates = h @ Uslice: 2 accumulators halve the dependent-MFMA chain
        f32x16 a0 = {0,0,0,0, 0,0,0,0, 0,0,0,0, 0,0,0,0};
        f32x16 a1 = {0,0,0,0, 0,0,0,0, 0,0,0,0, 0,0,0,0};
        #pragma unroll
        for (int kk = 0; kk < 16; kk++) {
            bf16x8 af0 = *(const bf16x8*)&h_lds[col][kk * 16 + half * 8];
            a0 = __builtin_amdgcn_mfma_f32_32x32x16_bf16(af0, ufrag[kk], a0, 0, 0, 0);
            bf16x8 af1 = *(const bf16x8*)&h_lds[col][(kk + 16) * 16 + half * 8];
            a1 = __builtin_amdgcn_mfma_f32_32x32x16_bf16(af1, ufrag[kk + 16], a1, 0, 0, 0);
        }

        // gate exchange (wave-local LDS; in-wave lgkmcnt ordering, no barrier)
        #pragma unroll
        for (int r = 0; r < 16; r++) {
            int b = (r & 3) + ((r >> 2) << 3) + (half << 2);
            float xwv = bf2f(r < 8 ? (u16)xv0[r] : (u16)xv1[r - 8]);
            gl[wave][b][col] = a0[r] + a1[r] + xwv;
        }

        // cell update: compute 4 results, then burst plain h stores
        u16 hv[4];
        int bi[4];
        #pragma unroll
        for (int i = 0; i < 4; i++) {
            int p = (i << 6) + lane, b = p >> 3, u = p & 7;
            f32x4 g4 = *(const f32x4*)&gl[wave][b][u << 2];   // i,f,g,o
            float si = fsig(g4[0]), sf = fsig(g4[1]);
            float sg = ftanh(g4[2]), so = fsig(g4[3]);
            float c = sf * cst[i] + si * sg;
            cst[i] = c;
            hv[i] = f2bf(so * ftanh(c));
            bi[i] = b;
        }
        u16* hb_out = hbuf + ((size_t)(((size_t)t + 1) & 1) << 14);
        const int j = (wg64 << 3);
        #pragma unroll
        for (int i = 0; i < 4; i++) {
            int p = (i << 6) + lane, u = p & 7;
            u32 hw = hv[i];
            u16* hp = hb_out + bi[i] * 512 + j + u;
            asm volatile("global_store_short %0, %1, off"
                         :: "v"(hp), "v"(hw) : "memory");
        }
        // drain to shared L2, WG barrier, publish per-WG flag (64B-strided)
        asm volatile("s_waitcnt vmcnt(0)" ::: "memory");
        __syncthreads();
        if (tid == 0) {
            u32 fv = (u32)(t + 1);
            u32* fq = flags + role * 16;
            asm volatile("global_store_dword %0, %1, off"
                         :: "v"(fq), "v"(fv) : "memory");
        }
        // hseq: plain cached stores, off the critical path
        #pragma unroll
        for (int i = 0; i < 4; i++) {
            int p = (i << 6) + lane, u = p & 7;
            hseq[((size_t)bi[i] * S_ + t) * NH_ + j + u] = hv[i];
        }
        // (a) xw prefetch for t+1 at the TAIL: ~1100cy head start before the
        // next stage vmcnt(0). Reads past xw end at t=1023 land in xbf (safe,
        // unused). Drained by next iteration's stage vmcnt(0).
        {
            const u16* xpn = xw + (((size_t)(t + 1) * 64 + wg64) * 64 + lane) * 16;
            asm volatile("global_load_dwordx4 %0, %2, off\n\t"
                         "global_load_dwordx4 %1, %2, off offset:16"
                         : "=&v"(xv0), "=&v"(xv1) : "v"(xpn) : "memory");
        }
    }
}

extern "C" void kernel_launch(void* const* d_in, const int* in_sizes, int n_in,
                              void* d_out, int out_size, void* d_ws, size_t ws_size,
                              hipStream_t stream) {
    const float* x        = (const float*)d_in[0];
    const float* W        = (const float*)d_in[1];
    const float* U        = (const float*)d_in[2];
    const float* hid_bias = (const float*)d_in[3];
    const float* V        = (const float*)d_in[4];
    const float* out_bias = (const float*)d_in[5];

    char* ws = (char*)d_ws;
    size_t off = 0;
    auto carve = [&](size_t bytes) -> void* {
        void* p = ws + off;
        off += (bytes + 255) & ~(size_t)255;
        return p;
    };
    u16* xw     = (u16*)carve((size_t)B_ * S_ * G4_ * 2);   // 128 MB, scan-order
    u16* xbf    = (u16*)carve((size_t)B_ * S_ * NH_ * 2);   //  32 MB
    u16* hseq   = (u16*)carve((size_t)B_ * S_ * NH_ * 2);   //  32 MB
    u16* WT     = (u16*)carve((size_t)G4_ * NH_ * 2);       //   2 MB
    u16* UT     = (u16*)carve((size_t)G4_ * NH_ * 2);       //   2 MB
    u16* VT     = (u16*)carve((size_t)NH_ * NH_ * 2);       // 512 KB
    u16* hbuf   = (u16*)carve((size_t)2 * B_ * NH_ * 2);    //  64 KB
    u32* flags  = (u32*)carve(1024);                        // 16 x 64B lines
    u32* elect  = (u32*)carve(256);
    int* winner = (int*)carve(256);

    hipMemsetAsync(flags, 0, 1024, stream);
    hipMemsetAsync(elect, 0, 256, stream);
    hipMemsetAsync(winner, 0xFF, 256, stream);   // winner = -1

    int n4 = B_ * S_ * NH_ / 4;
    cvt_bf16_kernel<<<(n4 + 255) / 256, 256, 0, stream>>>(x, xbf, n4);
    transpose_cvt_kernel<<<dim3(G4_ / 32, NH_ / 32), 256, 0, stream>>>(W, WT, NH_, G4_);
    transpose_cvt_kernel<<<dim3(G4_ / 32, NH_ / 32), 256, 0, stream>>>(U, UT, NH_, G4_);
    transpose_cvt_kernel<<<dim3(NH_ / 32, NH_ / 32), 256, 0, stream>>>(V, VT, NH_, NH_);

    // xW + hid_bias -> bf16, stored in scan order
    gemm_bf16_kernel<<<4096, 256, 0, stream>>>(xbf, WT, hid_bias, xw,
                                               B_ * S_, G4_, NH_, 1);
    // sequential LSTM scan (same-XCD election inside)
    lstm_scan_kernel<<<CAND, 256, 0, stream>>>(xw, UT, hseq, hbuf,
                                               flags, elect, winner);
    // out = hseq @ V + out_bias -> f32
    gemm_bf16_kernel<<<1024, 256, 0, stream>>>(hseq, VT, out_bias, d_out,
                                               B_ * S_, NH_, NH_, 0);
}

// Round 15
// 2825.954 us; speedup vs baseline: 1.1767x; 1.1727x over previous
//
#include <hip/hip_runtime.h>

typedef unsigned short u16;
typedef unsigned int   u32;
typedef unsigned long long u64;

typedef __attribute__((ext_vector_type(8)))  short bf16x8;
typedef __attribute__((ext_vector_type(4)))  float f32x4;
typedef __attribute__((ext_vector_type(8)))  u32   u32x8;
typedef __attribute__((ext_vector_type(16))) float f32x16;

#define B_  32
#define S_  1024
#define NH_ 512
#define G4_ 2048   // 4*NH
#define SC_NWG 16  // scan workgroups on the winning XCD (4 waves each) -- r12 optimum
#define CAND  256  // election candidates

__device__ __forceinline__ float bf2f(u16 h) {
    return __uint_as_float(((u32)h) << 16);
}
__device__ __forceinline__ u16 f2bf(float f) {
    u32 u = __float_as_uint(f);
    return (u16)((u + 0x7fffu + ((u >> 16) & 1u)) >> 16);
}
__device__ __forceinline__ float fsig(float x) {
    return 1.0f / (1.0f + __expf(-x));
}
__device__ __forceinline__ float ftanh(float x) {
    return 1.0f - 2.0f / (__expf(2.0f * x) + 1.0f);
}

// ---- fp32 [B][S][NH] -> bf16 TIME-MAJOR [(s*32+b)][NH] convert -------------
__global__ void cvt_bf16_kernel(const float* __restrict__ in, u16* __restrict__ out, int n4) {
    int i = blockIdx.x * blockDim.x + threadIdx.x;
    if (i >= n4) return;
    f32x4 v = ((const f32x4*)in)[i];
    u64 pk =
        (u64)f2bf(v[0]) |
        ((u64)f2bf(v[1]) << 16) |
        ((u64)f2bf(v[2]) << 32) |
        ((u64)f2bf(v[3]) << 48);
    int c4 = i & 127;               // NH/4 = 128 chunks per row
    int s  = (i >> 7) & 1023;
    int b  = i >> 17;
    ((u64*)out)[((size_t)(s * 32 + b)) * 128 + c4] = pk;
}

// ---------------- fp32 [R][C] -> bf16 [C][R] transpose-convert --------------
__global__ void transpose_cvt_kernel(const float* __restrict__ in, u16* __restrict__ out,
                                     int R, int C) {
    __shared__ float tile[32][33];
    int bx = blockIdx.x, by = blockIdx.y;
    int tx = threadIdx.x & 31, ty = threadIdx.x >> 5;
    #pragma unroll
    for (int i = 0; i < 4; i++) {
        int r = by * 32 + ty + i * 8;
        tile[ty + i * 8][tx] = in[(size_t)r * C + bx * 32 + tx];
    }
    __syncthreads();
    #pragma unroll
    for (int i = 0; i < 4; i++) {
        int c = bx * 32 + ty + i * 8;
        out[(size_t)c * R + by * 32 + tx] = f2bf(tile[tx][ty + i * 8]);
    }
}

// ---------------- generic bf16 MFMA GEMM: C = A @ BT^T + bias ---------------
// A [M][K] bf16 row-major, BT [N][K] bf16, bias [N] f32.
// out_mode 0: f32 row-major (m = row index of A).
// out_mode 1: bf16 scan-order [t][wg64][lane2][r2], assumes A rows are
//             TIME-MAJOR m = t*32 + b  -> 4 consecutive acc regs = 4
//             consecutive b = 4 consecutive r2 = ONE coalesced 8B store.
// Staging: global_load_lds width=16, linear [128][32] LDS (m97 structure).
__global__ __launch_bounds__(256) void gemm_bf16_kernel(
    const u16* __restrict__ A, const u16* __restrict__ BT,
    const float* __restrict__ bias, void* __restrict__ Cp,
    int M, int N, int K, int out_mode)
{
    __shared__ u16 Al[128][32];   // linear: global_load_lds needs lane-contiguous dest
    __shared__ u16 Bl[128][32];
    int nbm = M >> 7;
    int bm = blockIdx.x % nbm, bn = blockIdx.x / nbm;
    int tid = threadIdx.x, lane = tid & 63, wave = tid >> 6;
    int wr = wave >> 1, wc = wave & 1;
    f32x4 acc[4][4];
    #pragma unroll
    for (int i = 0; i < 4; i++)
        #pragma unroll
        for (int j = 0; j < 4; j++)
            acc[i][j] = (f32x4){0.f, 0.f, 0.f, 0.f};
    int fr  = lane & 15;
    int kof = (lane >> 4) << 3;

    for (int k0 = 0; k0 < K; k0 += 32) {
        __syncthreads();
        #pragma unroll
        for (int i = 0; i < 2; i++) {
            int chunk = i * 256 + tid;            // 512 chunks of 16B
            int r = chunk >> 2, c = (chunk & 3) << 3;
            __builtin_amdgcn_global_load_lds(
                (const __attribute__((address_space(1))) u32*)
                    &A[(size_t)(bm * 128 + r) * K + k0 + c],
                (__attribute__((address_space(3))) u32*)&Al[r][c], 16, 0, 0);
            __builtin_amdgcn_global_load_lds(
                (const __attribute__((address_space(1))) u32*)
                    &BT[(size_t)(bn * 128 + r) * K + k0 + c],
                (__attribute__((address_space(3))) u32*)&Bl[r][c], 16, 0, 0);
        }
        __syncthreads();   // compiler drains vmcnt before s_barrier
        bf16x8 af[4], bfr[4];
        #pragma unroll
        for (int mi = 0; mi < 4; mi++)
            af[mi] = *(const bf16x8*)&Al[wr * 64 + mi * 16 + fr][kof];
        #pragma unroll
        for (int ni = 0; ni < 4; ni++)
            bfr[ni] = *(const bf16x8*)&Bl[wc * 64 + ni * 16 + fr][kof];
        #pragma unroll
        for (int mi = 0; mi < 4; mi++)
            #pragma unroll
            for (int ni = 0; ni < 4; ni++)
                acc[mi][ni] = __builtin_amdgcn_mfma_f32_16x16x32_bf16(af[mi], bfr[ni], acc[mi][ni], 0, 0, 0);
    }
    int rq = lane >> 4;
    if (out_mode == 1) {
        #pragma unroll
        for (int mi = 0; mi < 4; mi++) {
            int m0 = bm * 128 + wr * 64 + mi * 16 + rq * 4;  // aligned-4, no t carry
            int t  = m0 >> 5, B0 = m0 & 31;
            #pragma unroll
            for (int ni = 0; ni < 4; ni++) {
                int n = bn * 128 + wc * 64 + ni * 16 + fr;
                float bv = bias[n];
                int g_loc = n >> 9, wg64i = (n >> 3) & 63, u_loc = n & 7;
                int lane2 = (((B0 >> 2) & 1) << 5) | (u_loc << 2) | g_loc;
                u64 pk =
                    (u64)f2bf(acc[mi][ni][0] + bv) |
                    ((u64)f2bf(acc[mi][ni][1] + bv) << 16) |
                    ((u64)f2bf(acc[mi][ni][2] + bv) << 32) |
                    ((u64)f2bf(acc[mi][ni][3] + bv) << 48);
                ((u64*)Cp)[(((size_t)t * 64 + wg64i) * 64 + lane2) * 4 + (B0 >> 3)] = pk;
            }
        }
    } else {
        #pragma unroll
        for (int mi = 0; mi < 4; mi++) {
            #pragma unroll
            for (int ni = 0; ni < 4; ni++) {
                int n = bn * 128 + wc * 64 + ni * 16 + fr;
                float bv = bias ? bias[n] : 0.f;
                #pragma unroll
                for (int r = 0; r < 4; r++) {
                    int m = bm * 128 + wr * 64 + mi * 16 + rq * 4 + r;
                    ((float*)Cp)[(size_t)m * N + n] = acc[mi][ni][r] + bv;
                }
            }
        }
    }
}

// ---------------- LSTM scan: 16 same-XCD WGs x 4 waves (EXACT r12) ----------
// Validated best: scan 2595us, FETCH 66MB. Election -> intra-XCD L2
// messaging; scalar-cache poll (s_dcache_inv + s_load_dwordx8 x2); one
// buffer_inv + plain bulk reads; plain h stores -> vmcnt(0) -> barrier ->
// per-WG flag. 40KB LDS pad (live via volatile read) -> 1 WG/CU.
__global__ __launch_bounds__(256, 1) void lstm_scan_kernel(
    const u16* __restrict__ xw,    // [S][64][64][16] bf16 scan-order
    const u16* __restrict__ UT,    // [4H][NH] bf16
    u16* __restrict__ hseq,        // [B][S][NH] bf16
    u16* __restrict__ hbuf,        // [2][32][512] bf16
    u32* __restrict__ flags,       // [16] per-WG progress
    u32* __restrict__ elect,       // [8] per-XCD registration counters
    int* __restrict__ winner)      // winning XCD id, init -1
{
    __shared__ int s_role;
    __shared__ u16 h_lds[32][520];      // [batch][k], +8 u16 pad (0-conflict, r2)
    __shared__ float gl[4][32][32];     // per-wave gate exchange
    __shared__ u32 lds_pad[10240];      // 40KB occupancy pad -> 1 WG/CU

    const int tid = threadIdx.x;

    lds_pad[tid] = (u32)tid;
    {
        volatile u32* vp = lds_pad;
        u32 dummy = vp[tid];
        asm volatile("" :: "v"(dummy));
    }

    if (tid == 0) {
        u32 xcc;
        asm volatile("s_getreg_b32 %0, hwreg(HW_REG_XCC_ID)" : "=s"(xcc));
        xcc &= 7u;
        u32 r = __hip_atomic_fetch_add(&elect[xcc], 1u,
                    __ATOMIC_ACQ_REL, __HIP_MEMORY_SCOPE_AGENT);
        int role = -1;
        if (r < (u32)SC_NWG) {
            if (r == (u32)SC_NWG - 1) {
                int expv = -1;
                __hip_atomic_compare_exchange_strong(winner, &expv, (int)xcc,
                    __ATOMIC_ACQ_REL, __ATOMIC_ACQUIRE, __HIP_MEMORY_SCOPE_AGENT);
            }
            int w = -1;
            for (int spins = 0; spins < 200000; spins++) {
                w = __hip_atomic_load(winner, __ATOMIC_ACQUIRE,
                                      __HIP_MEMORY_SCOPE_AGENT);
                if (w >= 0) break;
                __builtin_amdgcn_s_sleep(8);
            }
            role = (w == (int)xcc) ? (int)r : -1;
        }
        s_role = role;
    }
    __syncthreads();
    const int role = s_role;
    if (role < 0) return;

    const int wave = tid >> 6, lane = tid & 63;
    const int wg64 = role * 4 + wave;
    const int col  = lane & 31, half = lane >> 5;
    const int u_loc = col >> 2, g_loc = col & 3;
    const int ucol  = g_loc * 512 + wg64 * 8 + u_loc;

    // U B-fragments (asm loads, r11)
    bf16x8 ufrag[32];
    {
        const u16* ub = &UT[(size_t)ucol * 512 + half * 8];
        #define LDU4(i0)                                                      \
            asm volatile(                                                     \
                "global_load_dwordx4 %0, %4, off\n\t"                         \
                "global_load_dwordx4 %1, %4, off offset:32\n\t"               \
                "global_load_dwordx4 %2, %4, off offset:64\n\t"               \
                "global_load_dwordx4 %3, %4, off offset:96"                   \
                : "=&v"(ufrag[i0]), "=&v"(ufrag[i0 + 1]),                     \
                  "=&v"(ufrag[i0 + 2]), "=&v"(ufrag[i0 + 3])                  \
                : "v"(ub + (i0) * 16))
        LDU4(0); LDU4(4); LDU4(8); LDU4(12);
        LDU4(16); LDU4(20); LDU4(24); LDU4(28);
        #undef LDU4
        asm volatile("s_waitcnt vmcnt(0)" ::: "memory");
    }

    float cst[4] = {0.f, 0.f, 0.f, 0.f};

    // h(0) = 0 in LDS (t=0 skips the poll)
    {
        bf16x8 z = (bf16x8){0, 0, 0, 0, 0, 0, 0, 0};
        bf16x8* hf = (bf16x8*)&h_lds[0][0];
        for (int i = tid; i < 2080; i += 256) hf[i] = z;
    }

    const int sb_b  = tid >> 4;   // base row 0..15 (handles sb_b, sb_b+16)
    const int sb_ic = tid & 15;   // 16B chunk, 256B-strided (0-conflict, r2)

    for (int t = 0; t < 1024; t++) {
        // xw for this step: 32B contiguous per lane, issued early
        const u16* xp = xw + ((size_t)((size_t)t * 64 + wg64) * 64 + lane) * 16;
        bf16x8 xv0 = *(const bf16x8*)xp;
        bf16x8 xv1 = *(const bf16x8*)(xp + 8);

        if (t > 0) {
            const u32 tg = (u32)t;
            // scalar-cache poll: 2 SMEM ops/wave/round, contention-free
            {
                u32x8 f0, f1;
                int rounds = 0;
                while (1) {
                    asm volatile("s_dcache_inv\n\t"
                                 "s_load_dwordx8 %0, %2, 0x0\n\t"
                                 "s_load_dwordx8 %1, %2, 0x20\n\t"
                                 "s_waitcnt lgkmcnt(0)"
                                 : "=s"(f0), "=s"(f1) : "s"(flags) : "memory");
                    bool ok = f0[0] >= tg && f0[1] >= tg && f0[2] >= tg &&
                              f0[3] >= tg && f0[4] >= tg && f0[5] >= tg &&
                              f0[6] >= tg && f0[7] >= tg &&
                              f1[0] >= tg && f1[1] >= tg && f1[2] >= tg &&
                              f1[3] >= tg && f1[4] >= tg && f1[5] >= tg &&
                              f1[6] >= tg && f1[7] >= tg;
                    if (ok || ++rounds > (1 << 13)) break;
                }
            }
            // one L1 invalidate, then plain bulk reads served by shared L2
            asm volatile("buffer_inv" ::: "memory");
            const char* sb0 = (const char*)(hbuf + ((size_t)(t & 1) << 14))
                              + sb_b * 1024 + sb_ic * 16;
            f32x4 r0, r1, r2, r3, r4, r5, r6, r7;
            asm volatile(
                "global_load_dwordx4 %0, %8, off\n\t"
                "global_load_dwordx4 %1, %8, off offset:256\n\t"
                "global_load_dwordx4 %2, %8, off offset:512\n\t"
                "global_load_dwordx4 %3, %8, off offset:768\n\t"
                "global_load_dwordx4 %4, %9, off\n\t"
                "global_load_dwordx4 %5, %9, off offset:256\n\t"
                "global_load_dwordx4 %6, %9, off offset:512\n\t"
                "global_load_dwordx4 %7, %9, off offset:768\n\t"
                "s_waitcnt vmcnt(0)"
                : "=&v"(r0), "=&v"(r1), "=&v"(r2), "=&v"(r3),
                  "=&v"(r4), "=&v"(r5), "=&v"(r6), "=&v"(r7)
                : "v"(sb0), "v"(sb0 + 16384) : "memory");
            __builtin_amdgcn_sched_barrier(0);
            u16* d0 = &h_lds[sb_b][sb_ic * 8];
            u16* d1 = &h_lds[sb_b + 16][sb_ic * 8];
            *(f32x4*)(d0)       = r0;
            *(f32x4*)(d0 + 128) = r1;
            *(f32x4*)(d0 + 256) = r2;
            *(f32x4*)(d0 + 384) = r3;
            *(f32x4*)(d1)       = r4;
            *(f32x4*)(d1 + 128) = r5;
            *(f32x4*)(d1 + 256) = r6;
            *(f32x4*)(d1 + 384) = r7;
        }
        __syncthreads();

        // gates = h @ Uslice: 2 accumulators halve the dependent-MFMA chain
        f32x16 a0 = {0,0,0,0, 0,0,0,0, 0,0,0,0, 0,0,0,0};
        f32x16 a1 = {0,0,0,0, 0,0,0,0, 0,0,0,0, 0,0,0,0};
        #pragma unroll
        for (int kk = 0; kk < 16; kk++) {
            bf16x8 af0 = *(const bf16x8*)&h_lds[col][kk * 16 + half * 8];
            a0 = __builtin_amdgcn_mfma_f32_32x32x16_bf16(af0, ufrag[kk], a0, 0, 0, 0);
            bf16x8 af1 = *(const bf16x8*)&h_lds[col][(kk + 16) * 16 + half * 8];
            a1 = __builtin_amdgcn_mfma_f32_32x32x16_bf16(af1, ufrag[kk + 16], a1, 0, 0, 0);
        }

        // gate exchange (wave-local LDS; in-wave lgkmcnt ordering, no barrier)
        #pragma unroll
        for (int r = 0; r < 16; r++) {
            int b = (r & 3) + ((r >> 2) << 3) + (half << 2);
            float xwv = bf2f(r < 8 ? (u16)xv0[r] : (u16)xv1[r - 8]);
            gl[wave][b][col] = a0[r] + a1[r] + xwv;
        }

        // cell update: compute 4 results, then burst plain h stores
        u16 hv[4];
        int bi[4];
        #pragma unroll
        for (int i = 0; i < 4; i++) {
            int p = (i << 6) + lane, b = p >> 3, u = p & 7;
            f32x4 g4 = *(const f32x4*)&gl[wave][b][u << 2];   // i,f,g,o
            float si = fsig(g4[0]), sf = fsig(g4[1]);
            float sg = ftanh(g4[2]), so = fsig(g4[3]);
            float c = sf * cst[i] + si * sg;
            cst[i] = c;
            hv[i] = f2bf(so * ftanh(c));
            bi[i] = b;
        }
        u16* hb_out = hbuf + ((size_t)(((size_t)t + 1) & 1) << 14);
        const int j = (wg64 << 3);
        #pragma unroll
        for (int i = 0; i < 4; i++) {
            int p = (i << 6) + lane, u = p & 7;
            u32 hw = hv[i];
            u16* hp = hb_out + bi[i] * 512 + j + u;
            asm volatile("global_store_short %0, %1, off"
                         :: "v"(hp), "v"(hw) : "memory");
        }
        // drain to shared L2, WG barrier, publish per-WG flag
        asm volatile("s_waitcnt vmcnt(0)" ::: "memory");
        __syncthreads();
        if (tid == 0) {
            u32 fv = (u32)(t + 1);
            u32* fq = flags + role;
            asm volatile("global_store_dword %0, %1, off"
                         :: "v"(fq), "v"(fv) : "memory");
        }
        // hseq: plain cached stores, off the critical path
        #pragma unroll
        for (int i = 0; i < 4; i++) {
            int p = (i << 6) + lane, u = p & 7;
            hseq[((size_t)bi[i] * S_ + t) * NH_ + j + u] = hv[i];
        }
    }
}

extern "C" void kernel_launch(void* const* d_in, const int* in_sizes, int n_in,
                              void* d_out, int out_size, void* d_ws, size_t ws_size,
                              hipStream_t stream) {
    const float* x        = (const float*)d_in[0];
    const float* W        = (const float*)d_in[1];
    const float* U        = (const float*)d_in[2];
    const float* hid_bias = (const float*)d_in[3];
    const float* V        = (const float*)d_in[4];
    const float* out_bias = (const float*)d_in[5];

    char* ws = (char*)d_ws;
    size_t off = 0;
    auto carve = [&](size_t bytes) -> void* {
        void* p = ws + off;
        off += (bytes + 255) & ~(size_t)255;
        return p;
    };
    u16* xw     = (u16*)carve((size_t)B_ * S_ * G4_ * 2);   // 128 MB, scan-order
    u16* xbf    = (u16*)carve((size_t)B_ * S_ * NH_ * 2);   //  32 MB, time-major
    u16* hseq   = (u16*)carve((size_t)B_ * S_ * NH_ * 2);   //  32 MB
    u16* WT     = (u16*)carve((size_t)G4_ * NH_ * 2);       //   2 MB
    u16* UT     = (u16*)carve((size_t)G4_ * NH_ * 2);       //   2 MB
    u16* VT     = (u16*)carve((size_t)NH_ * NH_ * 2);       // 512 KB
    u16* hbuf   = (u16*)carve((size_t)2 * B_ * NH_ * 2);    //  64 KB
    u32* flags  = (u32*)carve(256);
    u32* elect  = (u32*)carve(256);
    int* winner = (int*)carve(256);

    hipMemsetAsync(flags, 0, 256, stream);
    hipMemsetAsync(elect, 0, 256, stream);
    hipMemsetAsync(winner, 0xFF, 256, stream);   // winner = -1

    int n4 = B_ * S_ * NH_ / 4;
    cvt_bf16_kernel<<<(n4 + 255) / 256, 256, 0, stream>>>(x, xbf, n4);
    transpose_cvt_kernel<<<dim3(G4_ / 32, NH_ / 32), 256, 0, stream>>>(W, WT, NH_, G4_);
    transpose_cvt_kernel<<<dim3(G4_ / 32, NH_ / 32), 256, 0, stream>>>(U, UT, NH_, G4_);
    transpose_cvt_kernel<<<dim3(NH_ / 32, NH_ / 32), 256, 0, stream>>>(V, VT, NH_, NH_);

    // xW + hid_bias -> bf16 scan-order (A time-major -> coalesced epilogue)
    gemm_bf16_kernel<<<4096, 256, 0, stream>>>(xbf, WT, hid_bias, xw,
                                               B_ * S_, G4_, NH_, 1);
    // sequential LSTM scan (same-XCD election inside)
    lstm_scan_kernel<<<CAND, 256, 0, stream>>>(xw, UT, hseq, hbuf,
                                               flags, elect, winner);
    // out = hseq @ V + out_bias -> f32
    gemm_bf16_kernel<<<1024, 256, 0, stream>>>(hseq, VT, out_bias, d_out,
                                               B_ * S_, NH_, NH_, 0);
}

// Round 16
// 2781.317 us; speedup vs baseline: 1.1956x; 1.0160x over previous
//
#include <hip/hip_runtime.h>

typedef unsigned short u16;
typedef unsigned int   u32;
typedef unsigned long long u64;

typedef __attribute__((ext_vector_type(8)))  short bf16x8;
typedef __attribute__((ext_vector_type(4)))  float f32x4;
typedef __attribute__((ext_vector_type(8)))  u32   u32x8;
typedef __attribute__((ext_vector_type(16))) float f32x16;

#define B_  32
#define S_  1024
#define NH_ 512
#define G4_ 2048   // 4*NH
#define SC_NWG 16  // scan workgroups on the winning XCD (4 waves each) -- r12 optimum
#define CAND  256  // election candidates

__device__ __forceinline__ float bf2f(u16 h) {
    return __uint_as_float(((u32)h) << 16);
}
__device__ __forceinline__ u16 f2bf(float f) {
    u32 u = __float_as_uint(f);
    return (u16)((u + 0x7fffu + ((u >> 16) & 1u)) >> 16);
}
__device__ __forceinline__ float fsig(float x) {
    return 1.0f / (1.0f + __expf(-x));
}
__device__ __forceinline__ float ftanh(float x) {
    return 1.0f - 2.0f / (__expf(2.0f * x) + 1.0f);
}

// ---- fp32 [B][S][NH] -> bf16 TIME-MAJOR [(s*32+b)][NH] convert -------------
__global__ void cvt_bf16_kernel(const float* __restrict__ in, u16* __restrict__ out, int n4) {
    int i = blockIdx.x * blockDim.x + threadIdx.x;
    if (i >= n4) return;
    f32x4 v = ((const f32x4*)in)[i];
    u64 pk =
        (u64)f2bf(v[0]) |
        ((u64)f2bf(v[1]) << 16) |
        ((u64)f2bf(v[2]) << 32) |
        ((u64)f2bf(v[3]) << 48);
    int c4 = i & 127;               // NH/4 = 128 chunks per row
    int s  = (i >> 7) & 1023;
    int b  = i >> 17;
    ((u64*)out)[((size_t)(s * 32 + b)) * 128 + c4] = pk;
}

// ---------------- fp32 [R][C] -> bf16 [C][R] transpose-convert --------------
__global__ void transpose_cvt_kernel(const float* __restrict__ in, u16* __restrict__ out,
                                     int R, int C) {
    __shared__ float tile[32][33];
    int bx = blockIdx.x, by = blockIdx.y;
    int tx = threadIdx.x & 31, ty = threadIdx.x >> 5;
    #pragma unroll
    for (int i = 0; i < 4; i++) {
        int r = by * 32 + ty + i * 8;
        tile[ty + i * 8][tx] = in[(size_t)r * C + bx * 32 + tx];
    }
    __syncthreads();
    #pragma unroll
    for (int i = 0; i < 4; i++) {
        int c = bx * 32 + ty + i * 8;
        out[(size_t)c * R + by * 32 + tx] = f2bf(tile[tx][ty + i * 8]);
    }
}

// ---------------- generic bf16 MFMA GEMM: C = A @ BT^T + bias ---------------
// A [M][K] bf16 row-major, BT [N][K] bf16, bias [N] f32.
// out_mode 0: f32 row-major (m = row index of A).
// out_mode 1: bf16 scan-order [t][wg64][lane2][r2], A rows TIME-MAJOR
//             m = t*32+b -> one coalesced 8B store per register quad.
// out_mode 2: f32, A rows TIME-MAJOR m = t*32+b, output row = b*1024 + t
//             (un-permutes the time-major hseq back to [B][S][NO]).
// Staging: global_load_lds width=16, linear [128][32] LDS (m97 structure).
__global__ __launch_bounds__(256) void gemm_bf16_kernel(
    const u16* __restrict__ A, const u16* __restrict__ BT,
    const float* __restrict__ bias, void* __restrict__ Cp,
    int M, int N, int K, int out_mode)
{
    __shared__ u16 Al[128][32];   // linear: global_load_lds needs lane-contiguous dest
    __shared__ u16 Bl[128][32];
    int nbm = M >> 7;
    int bm = blockIdx.x % nbm, bn = blockIdx.x / nbm;
    int tid = threadIdx.x, lane = tid & 63, wave = tid >> 6;
    int wr = wave >> 1, wc = wave & 1;
    f32x4 acc[4][4];
    #pragma unroll
    for (int i = 0; i < 4; i++)
        #pragma unroll
        for (int j = 0; j < 4; j++)
            acc[i][j] = (f32x4){0.f, 0.f, 0.f, 0.f};
    int fr  = lane & 15;
    int kof = (lane >> 4) << 3;

    for (int k0 = 0; k0 < K; k0 += 32) {
        __syncthreads();
        #pragma unroll
        for (int i = 0; i < 2; i++) {
            int chunk = i * 256 + tid;            // 512 chunks of 16B
            int r = chunk >> 2, c = (chunk & 3) << 3;
            __builtin_amdgcn_global_load_lds(
                (const __attribute__((address_space(1))) u32*)
                    &A[(size_t)(bm * 128 + r) * K + k0 + c],
                (__attribute__((address_space(3))) u32*)&Al[r][c], 16, 0, 0);
            __builtin_amdgcn_global_load_lds(
                (const __attribute__((address_space(1))) u32*)
                    &BT[(size_t)(bn * 128 + r) * K + k0 + c],
                (__attribute__((address_space(3))) u32*)&Bl[r][c], 16, 0, 0);
        }
        __syncthreads();   // compiler drains vmcnt before s_barrier
        bf16x8 af[4], bfr[4];
        #pragma unroll
        for (int mi = 0; mi < 4; mi++)
            af[mi] = *(const bf16x8*)&Al[wr * 64 + mi * 16 + fr][kof];
        #pragma unroll
        for (int ni = 0; ni < 4; ni++)
            bfr[ni] = *(const bf16x8*)&Bl[wc * 64 + ni * 16 + fr][kof];
        #pragma unroll
        for (int mi = 0; mi < 4; mi++)
            #pragma unroll
            for (int ni = 0; ni < 4; ni++)
                acc[mi][ni] = __builtin_amdgcn_mfma_f32_16x16x32_bf16(af[mi], bfr[ni], acc[mi][ni], 0, 0, 0);
    }
    int rq = lane >> 4;
    if (out_mode == 1) {
        #pragma unroll
        for (int mi = 0; mi < 4; mi++) {
            int m0 = bm * 128 + wr * 64 + mi * 16 + rq * 4;  // aligned-4, no t carry
            int t  = m0 >> 5, B0 = m0 & 31;
            #pragma unroll
            for (int ni = 0; ni < 4; ni++) {
                int n = bn * 128 + wc * 64 + ni * 16 + fr;
                float bv = bias[n];
                int g_loc = n >> 9, wg64i = (n >> 3) & 63, u_loc = n & 7;
                int lane2 = (((B0 >> 2) & 1) << 5) | (u_loc << 2) | g_loc;
                u64 pk =
                    (u64)f2bf(acc[mi][ni][0] + bv) |
                    ((u64)f2bf(acc[mi][ni][1] + bv) << 16) |
                    ((u64)f2bf(acc[mi][ni][2] + bv) << 32) |
                    ((u64)f2bf(acc[mi][ni][3] + bv) << 48);
                ((u64*)Cp)[(((size_t)t * 64 + wg64i) * 64 + lane2) * 4 + (B0 >> 3)] = pk;
            }
        }
    } else {
        #pragma unroll
        for (int mi = 0; mi < 4; mi++) {
            #pragma unroll
            for (int ni = 0; ni < 4; ni++) {
                int n = bn * 128 + wc * 64 + ni * 16 + fr;
                float bv = bias ? bias[n] : 0.f;
                #pragma unroll
                for (int r = 0; r < 4; r++) {
                    int m = bm * 128 + wr * 64 + mi * 16 + rq * 4 + r;
                    size_t orow = (out_mode == 2)
                        ? (((size_t)(m & 31) << 10) | (size_t)(m >> 5))
                        : (size_t)m;
                    ((float*)Cp)[orow * N + n] = acc[mi][ni][r] + bv;
                }
            }
        }
    }
}

// ---------------- LSTM scan: 16 same-XCD WGs x 4 waves (r12 protocol) -------
// Validated best protocol (scan 2595us, FETCH 66MB). ONE change this round:
// hseq is stored TIME-MAJOR [(t*32+b)][NH]. The WG's 4 waves then write 32
// rows x 128B CONTIGUOUS per step (vs 128 scattered 16B segments on 1KB-
// strided lines) -- the next step's bulk-read vmcnt(0) no longer waits on
// scattered cold-line store acks, and L2 churn during the poll drops 4x.
__global__ __launch_bounds__(256, 1) void lstm_scan_kernel(
    const u16* __restrict__ xw,    // [S][64][64][16] bf16 scan-order
    const u16* __restrict__ UT,    // [4H][NH] bf16
    u16* __restrict__ hseq,        // [(t*32+b)][NH] bf16 TIME-MAJOR
    u16* __restrict__ hbuf,        // [2][32][512] bf16
    u32* __restrict__ flags,       // [16] per-WG progress
    u32* __restrict__ elect,       // [8] per-XCD registration counters
    int* __restrict__ winner)      // winning XCD id, init -1
{
    __shared__ int s_role;
    __shared__ u16 h_lds[32][520];      // [batch][k], +8 u16 pad (0-conflict, r2)
    __shared__ float gl[4][32][32];     // per-wave gate exchange
    __shared__ u32 lds_pad[10240];      // 40KB occupancy pad -> 1 WG/CU

    const int tid = threadIdx.x;

    lds_pad[tid] = (u32)tid;
    {
        volatile u32* vp = lds_pad;
        u32 dummy = vp[tid];
        asm volatile("" :: "v"(dummy));
    }

    if (tid == 0) {
        u32 xcc;
        asm volatile("s_getreg_b32 %0, hwreg(HW_REG_XCC_ID)" : "=s"(xcc));
        xcc &= 7u;
        u32 r = __hip_atomic_fetch_add(&elect[xcc], 1u,
                    __ATOMIC_ACQ_REL, __HIP_MEMORY_SCOPE_AGENT);
        int role = -1;
        if (r < (u32)SC_NWG) {
            if (r == (u32)SC_NWG - 1) {
                int expv = -1;
                __hip_atomic_compare_exchange_strong(winner, &expv, (int)xcc,
                    __ATOMIC_ACQ_REL, __ATOMIC_ACQUIRE, __HIP_MEMORY_SCOPE_AGENT);
            }
            int w = -1;
            for (int spins = 0; spins < 200000; spins++) {
                w = __hip_atomic_load(winner, __ATOMIC_ACQUIRE,
                                      __HIP_MEMORY_SCOPE_AGENT);
                if (w >= 0) break;
                __builtin_amdgcn_s_sleep(8);
            }
            role = (w == (int)xcc) ? (int)r : -1;
        }
        s_role = role;
    }
    __syncthreads();
    const int role = s_role;
    if (role < 0) return;

    const int wave = tid >> 6, lane = tid & 63;
    const int wg64 = role * 4 + wave;
    const int col  = lane & 31, half = lane >> 5;
    const int u_loc = col >> 2, g_loc = col & 3;
    const int ucol  = g_loc * 512 + wg64 * 8 + u_loc;

    // U B-fragments (asm loads, r11)
    bf16x8 ufrag[32];
    {
        const u16* ub = &UT[(size_t)ucol * 512 + half * 8];
        #define LDU4(i0)                                                      \
            asm volatile(                                                     \
                "global_load_dwordx4 %0, %4, off\n\t"                         \
                "global_load_dwordx4 %1, %4, off offset:32\n\t"               \
                "global_load_dwordx4 %2, %4, off offset:64\n\t"               \
                "global_load_dwordx4 %3, %4, off offset:96"                   \
                : "=&v"(ufrag[i0]), "=&v"(ufrag[i0 + 1]),                     \
                  "=&v"(ufrag[i0 + 2]), "=&v"(ufrag[i0 + 3])                  \
                : "v"(ub + (i0) * 16))
        LDU4(0); LDU4(4); LDU4(8); LDU4(12);
        LDU4(16); LDU4(20); LDU4(24); LDU4(28);
        #undef LDU4
        asm volatile("s_waitcnt vmcnt(0)" ::: "memory");
    }

    float cst[4] = {0.f, 0.f, 0.f, 0.f};

    // h(0) = 0 in LDS (t=0 skips the poll)
    {
        bf16x8 z = (bf16x8){0, 0, 0, 0, 0, 0, 0, 0};
        bf16x8* hf = (bf16x8*)&h_lds[0][0];
        for (int i = tid; i < 2080; i += 256) hf[i] = z;
    }

    const int sb_b  = tid >> 4;   // base row 0..15 (handles sb_b, sb_b+16)
    const int sb_ic = tid & 15;   // 16B chunk, 256B-strided (0-conflict, r2)

    for (int t = 0; t < 1024; t++) {
        // xw for this step: 32B contiguous per lane, issued early
        const u16* xp = xw + ((size_t)((size_t)t * 64 + wg64) * 64 + lane) * 16;
        bf16x8 xv0 = *(const bf16x8*)xp;
        bf16x8 xv1 = *(const bf16x8*)(xp + 8);

        if (t > 0) {
            const u32 tg = (u32)t;
            // scalar-cache poll: 2 SMEM ops/wave/round, contention-free
            {
                u32x8 f0, f1;
                int rounds = 0;
                while (1) {
                    asm volatile("s_dcache_inv\n\t"
                                 "s_load_dwordx8 %0, %2, 0x0\n\t"
                                 "s_load_dwordx8 %1, %2, 0x20\n\t"
                                 "s_waitcnt lgkmcnt(0)"
                                 : "=s"(f0), "=s"(f1) : "s"(flags) : "memory");
                    bool ok = f0[0] >= tg && f0[1] >= tg && f0[2] >= tg &&
                              f0[3] >= tg && f0[4] >= tg && f0[5] >= tg &&
                              f0[6] >= tg && f0[7] >= tg &&
                              f1[0] >= tg && f1[1] >= tg && f1[2] >= tg &&
                              f1[3] >= tg && f1[4] >= tg && f1[5] >= tg &&
                              f1[6] >= tg && f1[7] >= tg;
                    if (ok || ++rounds > (1 << 13)) break;
                }
            }
            // one L1 invalidate, then plain bulk reads served by shared L2
            asm volatile("buffer_inv" ::: "memory");
            const char* sb0 = (const char*)(hbuf + ((size_t)(t & 1) << 14))
                              + sb_b * 1024 + sb_ic * 16;
            f32x4 r0, r1, r2, r3, r4, r5, r6, r7;
            asm volatile(
                "global_load_dwordx4 %0, %8, off\n\t"
                "global_load_dwordx4 %1, %8, off offset:256\n\t"
                "global_load_dwordx4 %2, %8, off offset:512\n\t"
                "global_load_dwordx4 %3, %8, off offset:768\n\t"
                "global_load_dwordx4 %4, %9, off\n\t"
                "global_load_dwordx4 %5, %9, off offset:256\n\t"
                "global_load_dwordx4 %6, %9, off offset:512\n\t"
                "global_load_dwordx4 %7, %9, off offset:768\n\t"
                "s_waitcnt vmcnt(0)"
                : "=&v"(r0), "=&v"(r1), "=&v"(r2), "=&v"(r3),
                  "=&v"(r4), "=&v"(r5), "=&v"(r6), "=&v"(r7)
                : "v"(sb0), "v"(sb0 + 16384) : "memory");
            __builtin_amdgcn_sched_barrier(0);
            u16* d0 = &h_lds[sb_b][sb_ic * 8];
            u16* d1 = &h_lds[sb_b + 16][sb_ic * 8];
            *(f32x4*)(d0)       = r0;
            *(f32x4*)(d0 + 128) = r1;
            *(f32x4*)(d0 + 256) = r2;
            *(f32x4*)(d0 + 384) = r3;
            *(f32x4*)(d1)       = r4;
            *(f32x4*)(d1 + 128) = r5;
            *(f32x4*)(d1 + 256) = r6;
            *(f32x4*)(d1 + 384) = r7;
        }
        __syncthreads();

        // gates = h @ Uslice: 2 accumulators halve the dependent-MFMA chain
        f32x16 a0 = {0,0,0,0, 0,0,0,0, 0,0,0,0, 0,0,0,0};
        f32x16 a1 = {0,0,0,0, 0,0,0,0, 0,0,0,0, 0,0,0,0};
        #pragma unroll
        for (int kk = 0; kk < 16; kk++) {
            bf16x8 af0 = *(const bf16x8*)&h_lds[col][kk * 16 + half * 8];
            a0 = __builtin_amdgcn_mfma_f32_32x32x16_bf16(af0, ufrag[kk], a0, 0, 0, 0);
            bf16x8 af1 = *(const bf16x8*)&h_lds[col][(kk + 16) * 16 + half * 8];
            a1 = __builtin_amdgcn_mfma_f32_32x32x16_bf16(af1, ufrag[kk + 16], a1, 0, 0, 0);
        }

        // gate exchange (wave-local LDS; in-wave lgkmcnt ordering, no barrier)
        #pragma unroll
        for (int r = 0; r < 16; r++) {
            int b = (r & 3) + ((r >> 2) << 3) + (half << 2);
            float xwv = bf2f(r < 8 ? (u16)xv0[r] : (u16)xv1[r - 8]);
            gl[wave][b][col] = a0[r] + a1[r] + xwv;
        }

        // cell update: compute 4 results, then burst plain h stores
        u16 hv[4];
        int bi[4];
        #pragma unroll
        for (int i = 0; i < 4; i++) {
            int p = (i << 6) + lane, b = p >> 3, u = p & 7;
            f32x4 g4 = *(const f32x4*)&gl[wave][b][u << 2];   // i,f,g,o
            float si = fsig(g4[0]), sf = fsig(g4[1]);
            float sg = ftanh(g4[2]), so = fsig(g4[3]);
            float c = sf * cst[i] + si * sg;
            cst[i] = c;
            hv[i] = f2bf(so * ftanh(c));
            bi[i] = b;
        }
        u16* hb_out = hbuf + ((size_t)(((size_t)t + 1) & 1) << 14);
        const int j = (wg64 << 3);
        #pragma unroll
        for (int i = 0; i < 4; i++) {
            int p = (i << 6) + lane, u = p & 7;
            u32 hw = hv[i];
            u16* hp = hb_out + bi[i] * 512 + j + u;
            asm volatile("global_store_short %0, %1, off"
                         :: "v"(hp), "v"(hw) : "memory");
        }
        // drain to shared L2, WG barrier, publish per-WG flag
        asm volatile("s_waitcnt vmcnt(0)" ::: "memory");
        __syncthreads();
        if (tid == 0) {
            u32 fv = (u32)(t + 1);
            u32* fq = flags + role;
            asm volatile("global_store_dword %0, %1, off"
                         :: "v"(fq), "v"(fv) : "memory");
        }
        // hseq: TIME-MAJOR -> the WG's 4 waves write 32 rows x 128B
        // contiguous (coalesced, full-line), off the critical path
        #pragma unroll
        for (int i = 0; i < 4; i++) {
            int p = (i << 6) + lane, u = p & 7;
            hseq[((size_t)t * 32 + bi[i]) * NH_ + j + u] = hv[i];
        }
    }
}

extern "C" void kernel_launch(void* const* d_in, const int* in_sizes, int n_in,
                              void* d_out, int out_size, void* d_ws, size_t ws_size,
                              hipStream_t stream) {
    const float* x        = (const float*)d_in[0];
    const float* W        = (const float*)d_in[1];
    const float* U        = (const float*)d_in[2];
    const float* hid_bias = (const float*)d_in[3];
    const float* V        = (const float*)d_in[4];
    const float* out_bias = (const float*)d_in[5];

    char* ws = (char*)d_ws;
    size_t off = 0;
    auto carve = [&](size_t bytes) -> void* {
        void* p = ws + off;
        off += (bytes + 255) & ~(size_t)255;
        return p;
    };
    u16* xw     = (u16*)carve((size_t)B_ * S_ * G4_ * 2);   // 128 MB, scan-order
    u16* xbf    = (u16*)carve((size_t)B_ * S_ * NH_ * 2);   //  32 MB, time-major
    u16* hseq   = (u16*)carve((size_t)B_ * S_ * NH_ * 2);   //  32 MB, time-major
    u16* WT     = (u16*)carve((size_t)G4_ * NH_ * 2);       //   2 MB
    u16* UT     = (u16*)carve((size_t)G4_ * NH_ * 2);       //   2 MB
    u16* VT     = (u16*)carve((size_t)NH_ * NH_ * 2);       // 512 KB
    u16* hbuf   = (u16*)carve((size_t)2 * B_ * NH_ * 2);    //  64 KB
    u32* flags  = (u32*)carve(256);
    u32* elect  = (u32*)carve(256);
    int* winner = (int*)carve(256);

    hipMemsetAsync(flags, 0, 256, stream);
    hipMemsetAsync(elect, 0, 256, stream);
    hipMemsetAsync(winner, 0xFF, 256, stream);   // winner = -1

    int n4 = B_ * S_ * NH_ / 4;
    cvt_bf16_kernel<<<(n4 + 255) / 256, 256, 0, stream>>>(x, xbf, n4);
    transpose_cvt_kernel<<<dim3(G4_ / 32, NH_ / 32), 256, 0, stream>>>(W, WT, NH_, G4_);
    transpose_cvt_kernel<<<dim3(G4_ / 32, NH_ / 32), 256, 0, stream>>>(U, UT, NH_, G4_);
    transpose_cvt_kernel<<<dim3(NH_ / 32, NH_ / 32), 256, 0, stream>>>(V, VT, NH_, NH_);

    // xW + hid_bias -> bf16 scan-order (A time-major -> coalesced epilogue)
    gemm_bf16_kernel<<<4096, 256, 0, stream>>>(xbf, WT, hid_bias, xw,
                                               B_ * S_, G4_, NH_, 1);
    // sequential LSTM scan (same-XCD election inside)
    lstm_scan_kernel<<<CAND, 256, 0, stream>>>(xw, UT, hseq, hbuf,
                                               flags, elect, winner);
    // out = hseq(time-major) @ V + out_bias -> f32 [B][S][NO]
    gemm_bf16_kernel<<<1024, 256, 0, stream>>>(hseq, VT, out_bias, d_out,
                                               B_ * S_, NH_, NH_, 2);
}